// Round 1
// baseline (67.101 us; speedup 1.0000x reference)
//
#include <hip/hip_runtime.h>
#include <math.h>

#define N_WIRES 18
#define BATCH 64

// Closed-form evaluation of the quantum circuit:
//   theta[b,i] = (a[b,i]-min)/(max-min)*2pi - pi    (min/max over whole batch)
//   <Z_i>      = cos(alpha_i)cos(beta_i)cos(theta_i)
//                - sin(beta_i)sin(theta_i)*cos(theta_{i-1})*cos(theta_{i+1})
//   out[b]     = head_b + sum_i head_w[i] * <Z_i>
// Derivation: product state + diagonal CZ ladder (CZ: X_i -> Z_{i-1}X_iZ_{i+1})
// + Heisenberg U^dag Z U = cA*cB*Z + sA*cB*Y - sB*X; <Y>=0 on a real state.
__global__ __launch_bounds__(64) void qc_closed_form(
        const float* __restrict__ a,       // (BATCH, N_WIRES)
        const float* __restrict__ params,  // (N_WIRES, 3)
        const float* __restrict__ head_w,  // (1, N_WIRES)
        const float* __restrict__ head_b,  // (1,)
        float* __restrict__ out)           // (BATCH,)
{
    const int t = threadIdx.x;  // 0..63 — one thread per batch row; single wave

    // ---- global min/max over all BATCH*N_WIRES = 1152 elements ----
    float mn = 3.4028235e38f, mx = -3.4028235e38f;
    for (int i = t; i < BATCH * N_WIRES; i += 64) {
        float v = a[i];
        mn = fminf(mn, v);
        mx = fmaxf(mx, v);
    }
    // wave-64 butterfly reduction (single wave -> no __syncthreads needed)
    for (int off = 32; off > 0; off >>= 1) {
        mn = fminf(mn, __shfl_xor(mn, off));
        mx = fmaxf(mx, __shfl_xor(mx, off));
    }
    const float scale = 6.28318530717958647692f / (mx - mn);
    const float pi    = 3.14159265358979323846f;

    // ---- per-row angles ----
    float ct[N_WIRES], st[N_WIRES];
    const float* row = a + t * N_WIRES;
    #pragma unroll
    for (int i = 0; i < N_WIRES; ++i) {
        float th = (row[i] - mn) * scale - pi;
        float s, c;
        __sincosf(th, &s, &c);   // fast path; accuracy ~1e-6, threshold 1.8e-2
        ct[i] = c;
        st[i] = s;
    }

    // ---- closed-form expectation values + head ----
    float acc = head_b[0];
    #pragma unroll
    for (int i = 0; i < N_WIRES; ++i) {
        float alpha = params[i * 3 + 0];
        float beta  = params[i * 3 + 1];
        float w     = head_w[i];
        float cl = (i == 0)           ? 1.0f : ct[i - 1];
        float cr = (i == N_WIRES - 1) ? 1.0f : ct[i + 1];
        float ez = cosf(alpha) * cosf(beta) * ct[i]
                 - sinf(beta) * st[i] * cl * cr;
        acc = fmaf(w, ez, acc);
    }
    out[t] = acc;
}

extern "C" void kernel_launch(void* const* d_in, const int* in_sizes, int n_in,
                              void* d_out, int out_size, void* d_ws, size_t ws_size,
                              hipStream_t stream) {
    const float* a      = (const float*)d_in[0];  // state_batch (64,18)
    const float* params = (const float*)d_in[1];  // (18,3)
    const float* head_w = (const float*)d_in[2];  // (1,18)
    const float* head_b = (const float*)d_in[3];  // (1,)
    float* out = (float*)d_out;                   // (64,)
    qc_closed_form<<<1, 64, 0, stream>>>(a, params, head_w, head_b, out);
}

// Round 2
// 61.021 us; speedup vs baseline: 1.0996x; 1.0996x over previous
//
#include <hip/hip_runtime.h>
#include <math.h>

#define N_WIRES 18
#define BATCH 64
#define TOT (BATCH * N_WIRES)  // 1152

// Closed-form evaluation of the quantum circuit (derivation verified round 1, absmax 0.0):
//   theta[b,i] = (a[b,i]-min)/(max-min)*2pi - pi      (min/max over whole batch)
//   <Z_i>      = cos(alpha_i)cos(beta_i)cos(theta_i)
//                - sin(beta_i)sin(theta_i)*cos(theta_{i-1})*cos(theta_{i+1})
//   out[b]     = head_b + sum_i head_w[i] * <Z_i>
//
// Round-2 structure: single block, 256 threads (4 waves). All intermediate
// state in LDS (no per-thread arrays -> no scratch traffic), all trig in
// expression form __cosf/__sinf (inline v_cos/v_sin, no pointer-form sincos),
// rolled loops with trip count <=5 -> ~2 KB code (vs ~16 KB unrolled+libm in
// round 1, whose serialized cold I-fetch / scratch stalls cost 58 us).
__global__ __launch_bounds__(256) void qc_closed_form(
        const float* __restrict__ a,       // (BATCH, N_WIRES)
        const float* __restrict__ params,  // (N_WIRES, 3)
        const float* __restrict__ head_w,  // (1, N_WIRES)
        const float* __restrict__ head_b,  // (1,)
        float* __restrict__ out)           // (BATCH,)
{
    __shared__ float s_ct[TOT];     // cos(theta)
    __shared__ float s_st[TOT];     // sin(theta)
    __shared__ float s_term[TOT];   // head_w[i] * <Z_i> per (b,i)
    __shared__ float s_red[8];      // per-wave min (0..3) / max (4..7)

    const int tid = threadIdx.x;

    // ---- global min/max over 1152 elements ----
    float mn = 3.4028235e38f, mx = -3.4028235e38f;
    for (int j = tid; j < TOT; j += 256) {
        float v = a[j];
        mn = fminf(mn, v);
        mx = fmaxf(mx, v);
    }
    for (int off = 32; off > 0; off >>= 1) {
        mn = fminf(mn, __shfl_xor(mn, off));
        mx = fmaxf(mx, __shfl_xor(mx, off));
    }
    const int wave = tid >> 6;
    if ((tid & 63) == 0) { s_red[wave] = mn; s_red[4 + wave] = mx; }
    __syncthreads();
    mn = fminf(fminf(s_red[0], s_red[1]), fminf(s_red[2], s_red[3]));
    mx = fmaxf(fmaxf(s_red[4], s_red[5]), fmaxf(s_red[6], s_red[7]));
    const float scale = 6.28318530717958647692f / (mx - mn);
    const float pi    = 3.14159265358979323846f;

    // ---- angles -> LDS ----
    for (int j = tid; j < TOT; j += 256) {
        float th = (a[j] - mn) * scale - pi;
        s_ct[j] = __cosf(th);
        s_st[j] = __sinf(th);
    }
    __syncthreads();

    // ---- per-(b,i) closed-form term ----
    for (int j = tid; j < TOT; j += 256) {
        int i = j % N_WIRES;            // wire index (magic-mul, no div instr)
        float alpha = params[3 * i];
        float beta  = params[3 * i + 1];
        float cl = (i == 0)           ? 1.0f : s_ct[j - 1];
        float cr = (i == N_WIRES - 1) ? 1.0f : s_ct[j + 1];
        float ez = __cosf(alpha) * __cosf(beta) * s_ct[j]
                 - __sinf(beta) * s_st[j] * cl * cr;
        s_term[j] = head_w[i] * ez;
    }
    __syncthreads();

    // ---- row reduction + head ----
    if (tid < BATCH) {
        float acc = head_b[0];
        const float* t = s_term + tid * N_WIRES;
        for (int i = 0; i < N_WIRES; ++i) acc += t[i];
        out[tid] = acc;
    }
}

extern "C" void kernel_launch(void* const* d_in, const int* in_sizes, int n_in,
                              void* d_out, int out_size, void* d_ws, size_t ws_size,
                              hipStream_t stream) {
    const float* a      = (const float*)d_in[0];  // state_batch (64,18)
    const float* params = (const float*)d_in[1];  // (18,3)
    const float* head_w = (const float*)d_in[2];  // (1,18)
    const float* head_b = (const float*)d_in[3];  // (1,)
    float* out = (float*)d_out;                   // (64,)
    qc_closed_form<<<1, 256, 0, stream>>>(a, params, head_w, head_b, out);
}

// Round 3
// 59.303 us; speedup vs baseline: 1.1315x; 1.0290x over previous
//
#include <hip/hip_runtime.h>
#include <math.h>

#define N_WIRES 18
#define BATCH 64

// Closed-form evaluation of the quantum circuit (derivation verified: absmax 0.0
// in rounds 1-2):
//   theta[b,i] = (a[b,i]-min)/(max-min)*2pi - pi      (min/max over whole batch)
//   <Z_i>      = cos(alpha_i)cos(beta_i)cos(theta_i)
//                - sin(beta_i)sin(theta_i)*cos(theta_{i-1})*cos(theta_{i+1})
//   out[b]     = head_b + sum_i head_w[i]*<Z_i>
//
// Round-3 structure: ONE wave (64 threads), one batch row per thread, all state
// in registers (compile-time-indexed unrolled arrays -> no scratch). Per-wire
// coefficients cA_i = cos(a)cos(b)*w_i, cB_i = sin(b)*w_i computed once by
// lanes 0..17 into 144 B of LDS. Expression-form __cosf/__sinf only (inline
// v_cos/v_sin) -- round 1 showed libm cosf/sinf + pointer __sincosf cost 58 us
// in serialized cold I-fetch for a lone workgroup.
__global__ __launch_bounds__(64) void qc_closed_form(
        const float* __restrict__ a,       // (BATCH, N_WIRES)
        const float* __restrict__ params,  // (N_WIRES, 3)
        const float* __restrict__ head_w,  // (1, N_WIRES)
        const float* __restrict__ head_b,  // (1,)
        float* __restrict__ out)           // (BATCH,)
{
    const int t = threadIdx.x;  // 0..63 == batch row
    __shared__ float s_cA[N_WIRES];
    __shared__ float s_cB[N_WIRES];

    // per-wire coefficients (lanes 0..17), folded with head weights
    if (t < N_WIRES) {
        float al = params[3 * t];
        float be = params[3 * t + 1];
        float w  = head_w[t];
        s_cA[t] = __cosf(al) * __cosf(be) * w;
        s_cB[t] = __sinf(be) * w;
    }

    // row load -> registers (18 floats)
    float v[N_WIRES];
    const float* row = a + t * N_WIRES;
    #pragma unroll
    for (int i = 0; i < N_WIRES; ++i) v[i] = row[i];

    // global min/max: in-register over the row, then wave-64 butterfly
    float mn = v[0], mx = v[0];
    #pragma unroll
    for (int i = 1; i < N_WIRES; ++i) {
        mn = fminf(mn, v[i]);
        mx = fmaxf(mx, v[i]);
    }
    #pragma unroll
    for (int off = 32; off > 0; off >>= 1) {
        mn = fminf(mn, __shfl_xor(mn, off));
        mx = fmaxf(mx, __shfl_xor(mx, off));
    }
    const float scale = 6.28318530717958647692f / (mx - mn);
    const float pi    = 3.14159265358979323846f;

    // angles -> cos/sin in registers
    float ct[N_WIRES], st[N_WIRES];
    #pragma unroll
    for (int i = 0; i < N_WIRES; ++i) {
        float th = (v[i] - mn) * scale - pi;
        ct[i] = __cosf(th);
        st[i] = __sinf(th);
    }

    __syncthreads();  // single wave: just a waitcnt+barrier; makes s_cA/s_cB visible

    // closed-form accumulation
    float acc = head_b[0];
    #pragma unroll
    for (int i = 0; i < N_WIRES; ++i) {
        float cl = (i == 0)           ? 1.0f : ct[i - 1];
        float cr = (i == N_WIRES - 1) ? 1.0f : ct[i + 1];
        acc = fmaf(s_cA[i], ct[i], acc);
        acc -= s_cB[i] * st[i] * cl * cr;
    }
    out[t] = acc;
}

extern "C" void kernel_launch(void* const* d_in, const int* in_sizes, int n_in,
                              void* d_out, int out_size, void* d_ws, size_t ws_size,
                              hipStream_t stream) {
    const float* a      = (const float*)d_in[0];  // state_batch (64,18)
    const float* params = (const float*)d_in[1];  // (18,3)
    const float* head_w = (const float*)d_in[2];  // (1,18)
    const float* head_b = (const float*)d_in[3];  // (1,)
    float* out = (float*)d_out;                   // (64,)
    qc_closed_form<<<1, 64, 0, stream>>>(a, params, head_w, head_b, out);
}